// Round 2
// baseline (8008.684 us; speedup 1.0000x reference)
//
#include <hip/hip_runtime.h>
#include <hip/hip_cooperative_groups.h>

namespace cg = cooperative_groups;

// LSTM: L=2 layers, B=32, T=256, N=M=1024, gates 4M=4096
// d_in: x(B,T,N) h(L,B,M) c(L,B,M) Wih(L,4M,N) Whh(L,4M,M) bih(L,4M) bhh(L,4M), all fp32
// d_out: outs(B,T,M) ++ h_final(L,B,M) ++ c_final(L,B,M), fp32

typedef __bf16 bf16x8 __attribute__((ext_vector_type(8)));
typedef float  f32x4  __attribute__((ext_vector_type(4)));

__device__ __forceinline__ unsigned short f2bf(float f) {
    union { float f; unsigned u; } v; v.f = f;
    unsigned u = v.u;
    unsigned r = u + 0x7fffu + ((u >> 16) & 1u);   // RNE
    return (unsigned short)(r >> 16);
}
__device__ __forceinline__ float bf2f(unsigned short b) {
    union { unsigned u; float f; } v; v.u = ((unsigned)b) << 16;
    return v.f;
}
__device__ __forceinline__ float sigmoidf_fast(float x) {
    return 1.0f / (1.0f + __expf(-x));
}
// NaN-safe tanh: x->+inf gives 1-0, x->-inf gives 1-2 = -1
__device__ __forceinline__ float tanhf_fast(float x) {
    return 1.0f - 2.0f / (__expf(2.0f * x) + 1.0f);
}

__global__ void cvt_f32_to_bf16(const float* __restrict__ src,
                                unsigned short* __restrict__ dst, int n4) {
    int i = blockIdx.x * blockDim.x + threadIdx.x;
    int stride = gridDim.x * blockDim.x;
    for (; i < n4; i += stride) {
        float4 v = ((const float4*)src)[i];
        ushort4 o;
        o.x = f2bf(v.x); o.y = f2bf(v.y); o.z = f2bf(v.z); o.w = f2bf(v.w);
        ((ushort4*)dst)[i] = o;
    }
}

// C[r][j] = sum_k A[r][k]*W[j][k] + bih[j] + bhh[j]   (both K-contiguous, NT GEMM)
// A: R x 1024 bf16, W: 4096 x 1024 bf16, C: R x 4096 bf16. grid (R/64, 64), block 256.
__global__ __launch_bounds__(256) void gemm_proj(
    const unsigned short* __restrict__ A, const unsigned short* __restrict__ W,
    const float* __restrict__ bih, const float* __restrict__ bhh,
    unsigned short* __restrict__ C)
{
    __shared__ __align__(16) unsigned short Ash[64][40];
    __shared__ __align__(16) unsigned short Bsh[64][40];
    const int tid  = threadIdx.x;
    const int lane = tid & 63;
    const int w    = tid >> 6;
    const int wm   = w & 1, wn = w >> 1;
    const int row0 = blockIdx.x * 64;
    const int col0 = blockIdx.y * 64;
    const int srow = tid >> 2;
    const int sseg = (tid & 3) * 8;
    const int lrow = lane & 15;
    const int lk   = (lane >> 4) * 8;

    f32x4 acc[2][2] = {};

    for (int k0 = 0; k0 < 1024; k0 += 32) {
        __syncthreads();
        *(uint4*)&Ash[srow][sseg] = *(const uint4*)&A[(size_t)(row0 + srow) * 1024 + k0 + sseg];
        *(uint4*)&Bsh[srow][sseg] = *(const uint4*)&W[(size_t)(col0 + srow) * 1024 + k0 + sseg];
        __syncthreads();
        bf16x8 af[2], bfrag[2];
        af[0]    = *(const bf16x8*)&Ash[wm * 32 + lrow     ][lk];
        af[1]    = *(const bf16x8*)&Ash[wm * 32 + 16 + lrow][lk];
        bfrag[0] = *(const bf16x8*)&Bsh[wn * 32 + lrow     ][lk];
        bfrag[1] = *(const bf16x8*)&Bsh[wn * 32 + 16 + lrow][lk];
        #pragma unroll
        for (int i = 0; i < 2; i++)
            #pragma unroll
            for (int j = 0; j < 2; j++)
                acc[i][j] = __builtin_amdgcn_mfma_f32_16x16x32_bf16(af[i], bfrag[j], acc[i][j], 0, 0, 0);
    }

    #pragma unroll
    for (int i = 0; i < 2; i++) {
        int r = row0 + wm * 32 + i * 16 + (lane >> 4) * 4;
        #pragma unroll
        for (int j = 0; j < 2; j++) {
            int cc = col0 + wn * 32 + j * 16 + (lane & 15);
            float bsum = bih[cc] + bhh[cc];
            #pragma unroll
            for (int rr = 0; rr < 4; rr++)
                C[(size_t)(r + rr) * 4096 + cc] = f2bf(acc[i][j][rr] + bsum);
        }
    }
}

// Persistent recurrence for one layer: 64 blocks x 256 threads, cooperative launch.
// Block owns m in [m0,m0+16). Whole Whh slice (64 gate-rows x 1024) lives in VGPRs
// (32 x bf16x8 = 128 VGPR/lane). c-state lives in 2 regs/thread for all 256 steps.
// One grid.sync() per timestep.
__global__ __launch_bounds__(256, 1) void lstm_layer(
    const unsigned short* __restrict__ Whh,    // 4096 x 1024 bf16 (this layer)
    const unsigned short* __restrict__ xproj,  // (B,T,4M) bf16, bias folded
    unsigned short* __restrict__ h0buf,        // 32x1024 bf16, parity-0 (holds h_init)
    unsigned short* __restrict__ h1buf,        // 32x1024 bf16, parity-1 scratch
    const float* __restrict__ c0,              // 32x1024 f32 initial c (this layer)
    float* __restrict__ hF,                    // 32x1024 f32 final h -> d_out
    float* __restrict__ cF,                    // 32x1024 f32 final c -> d_out
    unsigned short* __restrict__ seq_bf,       // (B,T,M) bf16 or null
    float* __restrict__ seq_f32)               // (B,T,M) f32 or null
{
    cg::grid_group grid = cg::this_grid();

    __shared__ __align__(16) unsigned short hsh[32][1032];  // 32x1024 + 8 pad
    __shared__ __align__(16) float gsh[4][32][20];

    const int tid  = threadIdx.x;
    const int lane = tid & 63;
    const int w    = tid >> 6;
    const int m0   = blockIdx.x * 16;

    const int n  = lane & 15;
    const int vc = w * 16 + n;
    const int mi = vc >> 2;
    const int g  = vc & 3;
    const size_t jrow = (size_t)(g * 1024 + m0 + mi);
    const int lk = (lane >> 4) * 8;

    // --- stage Whh slice into registers (128 VGPR/lane) ---
    bf16x8 wreg[32];
    #pragma unroll
    for (int c = 0; c < 32; c++)
        wreg[c] = *(const bf16x8*)&Whh[jrow * 1024 + c * 32 + lk];

    // --- epilogue ownership: thread handles (b, m) for p=0,1 ---
    const int bbase = lane >> 2;          // 0..15
    const int ml    = lane & 3;
    const int m     = m0 + 4 * w + ml;
    float creg[2], hlast[2];
    #pragma unroll
    for (int p = 0; p < 2; p++)
        creg[p] = c0[(bbase + 16 * p) * 1024 + m];

    #pragma unroll 1
    for (int t = 0; t < 256; t++) {
        const unsigned short* hin = (t & 1) ? h1buf : h0buf;
        unsigned short* hout      = (t & 1) ? h0buf : h1buf;

        // prefetch xproj gate values (independent of h -> hides HBM latency)
        unsigned short xg[2][4];
        #pragma unroll
        for (int p = 0; p < 2; p++) {
            size_t xb = ((size_t)(bbase + 16 * p) * 256 + t) * 4096 + m;
            xg[p][0] = xproj[xb];
            xg[p][1] = xproj[xb + 1024];
            xg[p][2] = xproj[xb + 2048];
            xg[p][3] = xproj[xb + 3072];
        }

        // stage full h (32x1024 bf16 = 64KB) into LDS, coalesced
        #pragma unroll
        for (int s = 0; s < 16; s++) {
            int off = tid * 8 + s * 2048;
            int row = off >> 10;
            int col = off & 1023;
            *(uint4*)&hsh[row][col] = *(const uint4*)&hin[row * 1024 + col];
        }
        __syncthreads();

        // gates GEMM: 4 independent MFMA chains (K-parity x batch-half)
        f32x4 ae0 = {}, ae1 = {}, ao0 = {}, ao1 = {};
        #pragma unroll
        for (int c = 0; c < 32; c += 2) {
            bf16x8 a00 = *(const bf16x8*)&hsh[n     ][c * 32 + lk];
            bf16x8 a01 = *(const bf16x8*)&hsh[16 + n][c * 32 + lk];
            ae0 = __builtin_amdgcn_mfma_f32_16x16x32_bf16(a00, wreg[c], ae0, 0, 0, 0);
            ae1 = __builtin_amdgcn_mfma_f32_16x16x32_bf16(a01, wreg[c], ae1, 0, 0, 0);
            bf16x8 a10 = *(const bf16x8*)&hsh[n     ][(c + 1) * 32 + lk];
            bf16x8 a11 = *(const bf16x8*)&hsh[16 + n][(c + 1) * 32 + lk];
            ao0 = __builtin_amdgcn_mfma_f32_16x16x32_bf16(a10, wreg[c + 1], ao0, 0, 0, 0);
            ao1 = __builtin_amdgcn_mfma_f32_16x16x32_bf16(a11, wreg[c + 1], ao1, 0, 0, 0);
        }
        f32x4 acc0 = ae0 + ao0;
        f32x4 acc1 = ae1 + ao1;

        // wave-local gate exchange: C/D layout col=lane&15 (=n -> our vc), row=batch
        {
            int brow = (lane >> 4) * 4;
            #pragma unroll
            for (int r = 0; r < 4; r++) {
                gsh[w][brow + r][n]      = acc0[r];
                gsh[w][16 + brow + r][n] = acc1[r];
            }
        }
        __syncthreads();

        // elementwise cell update
        #pragma unroll
        for (int p = 0; p < 2; p++) {
            int b = bbase + 16 * p;
            const float4 gv = *(const float4*)&gsh[w][b][ml * 4];  // i,f,g,o
            float gi = gv.x + bf2f(xg[p][0]);
            float gf = gv.y + bf2f(xg[p][1]);
            float gg = gv.z + bf2f(xg[p][2]);
            float go = gv.w + bf2f(xg[p][3]);
            float i_ = sigmoidf_fast(gi);
            float f_ = sigmoidf_fast(gf);
            float g_ = tanhf_fast(gg);
            float o_ = sigmoidf_fast(go);
            float c_new = f_ * creg[p] + i_ * g_;
            float h_new = o_ * tanhf_fast(c_new);
            creg[p]  = c_new;
            hlast[p] = h_new;
            unsigned short hb = f2bf(h_new);
            hout[b * 1024 + m] = hb;
            size_t so = ((size_t)b * 256 + t) * 1024 + m;
            if (seq_bf)  seq_bf[so]  = hb;
            if (seq_f32) seq_f32[so] = h_new;
        }

        grid.sync();
    }

    // final states
    #pragma unroll
    for (int p = 0; p < 2; p++) {
        int b = bbase + 16 * p;
        hF[b * 1024 + m] = hlast[p];
        cF[b * 1024 + m] = creg[p];
    }
}

extern "C" void kernel_launch(void* const* d_in, const int* in_sizes, int n_in,
                              void* d_out, int out_size, void* d_ws, size_t ws_size,
                              hipStream_t stream)
{
    const float* x   = (const float*)d_in[0];
    const float* h0  = (const float*)d_in[1];
    const float* c0  = (const float*)d_in[2];
    const float* Wih = (const float*)d_in[3];
    const float* Whh = (const float*)d_in[4];
    const float* bih = (const float*)d_in[5];
    const float* bhh = (const float*)d_in[6];
    float* out = (float*)d_out;

    // workspace layout (~128.2 MB)
    char* p = (char*)d_ws;
    unsigned short* Xproj = (unsigned short*)p; p += (size_t)8192 * 4096 * 2;
    unsigned short* xbf   = (unsigned short*)p; p += (size_t)8192 * 1024 * 2;
    unsigned short* seqbf = (unsigned short*)p; p += (size_t)8192 * 1024 * 2;
    unsigned short* Wihbf = (unsigned short*)p; p += (size_t)2 * 4096 * 1024 * 2;
    unsigned short* Whhbf = (unsigned short*)p; p += (size_t)2 * 4096 * 1024 * 2;
    unsigned short* hbfA  = (unsigned short*)p; p += (size_t)2 * 32 * 1024 * 2;  // h_init both layers
    unsigned short* hbfB  = (unsigned short*)p; p += (size_t)32 * 1024 * 2;      // parity-1 scratch

    cvt_f32_to_bf16<<<1024, 256, 0, stream>>>(x,   xbf,   8192 * 1024 / 4);
    cvt_f32_to_bf16<<<1024, 256, 0, stream>>>(Wih, Wihbf, 2 * 4096 * 1024 / 4);
    cvt_f32_to_bf16<<<1024, 256, 0, stream>>>(Whh, Whhbf, 2 * 4096 * 1024 / 4);
    cvt_f32_to_bf16<<<64,   256, 0, stream>>>(h0,  hbfA,  2 * 32 * 1024 / 4);

    for (int l = 0; l < 2; l++) {
        const unsigned short* Ain = (l == 0) ? xbf : seqbf;
        gemm_proj<<<dim3(128, 64), 256, 0, stream>>>(
            Ain, Wihbf + (size_t)l * 4096 * 1024, bih + l * 4096, bhh + l * 4096, Xproj);

        const unsigned short* Whl = Whhbf + (size_t)l * 4096 * 1024;
        unsigned short* h0l = hbfA + l * 32 * 1024;
        unsigned short* h1l = hbfB;
        const float*    c0l = c0  + l * 32 * 1024;
        float* hFl = out + (size_t)8192 * 1024 + l * 32 * 1024;
        float* cFl = out + (size_t)8192 * 1024 + 65536 + l * 32 * 1024;
        unsigned short* sb = (l == 0) ? seqbf : nullptr;
        float* sf          = (l == 1) ? out   : nullptr;

        void* args[] = { (void*)&Whl, (void*)&Xproj, (void*)&h0l, (void*)&h1l,
                         (void*)&c0l, (void*)&hFl, (void*)&cFl, (void*)&sb, (void*)&sf };
        hipLaunchCooperativeKernel((const void*)lstm_layer, dim3(64), dim3(256),
                                   args, 0, stream);
    }
}

// Round 4
// 6465.650 us; speedup vs baseline: 1.2387x; 1.2387x over previous
//
#include <hip/hip_runtime.h>

// LSTM: L=2 layers, B=32, T=256, N=M=1024, gates 4M=4096
// d_in: x(B,T,N) h(L,B,M) c(L,B,M) Wih(L,4M,N) Whh(L,4M,M) bih(L,4M) bhh(L,4M), all fp32
// d_out: outs(B,T,M) ++ h_final(L,B,M) ++ c_final(L,B,M), fp32

typedef __bf16 bf16x8 __attribute__((ext_vector_type(8)));
typedef float  f32x4  __attribute__((ext_vector_type(4)));

__device__ __forceinline__ unsigned short f2bf(float f) {
    union { float f; unsigned u; } v; v.f = f;
    unsigned u = v.u;
    unsigned r = u + 0x7fffu + ((u >> 16) & 1u);   // RNE
    return (unsigned short)(r >> 16);
}
__device__ __forceinline__ float bf2f(unsigned short b) {
    union { unsigned u; float f; } v; v.u = ((unsigned)b) << 16;
    return v.f;
}
__device__ __forceinline__ float sigmoidf_fast(float x) {
    return 1.0f / (1.0f + __expf(-x));
}
__device__ __forceinline__ float tanhf_fast(float x) {
    return 1.0f - 2.0f / (__expf(2.0f * x) + 1.0f);
}

__global__ void cvt_f32_to_bf16(const float* __restrict__ src,
                                unsigned short* __restrict__ dst, int n4) {
    int i = blockIdx.x * blockDim.x + threadIdx.x;
    int stride = gridDim.x * blockDim.x;
    for (; i < n4; i += stride) {
        float4 v = ((const float4*)src)[i];
        ushort4 o;
        o.x = f2bf(v.x); o.y = f2bf(v.y); o.z = f2bf(v.z); o.w = f2bf(v.w);
        ((ushort4*)dst)[i] = o;
    }
}

// C[r][j] = sum_k A[r][k]*W[j][k] + bih[j] + bhh[j]   (NT GEMM)
__global__ __launch_bounds__(256) void gemm_proj(
    const unsigned short* __restrict__ A, const unsigned short* __restrict__ W,
    const float* __restrict__ bih, const float* __restrict__ bhh,
    unsigned short* __restrict__ C)
{
    __shared__ __align__(16) unsigned short Ash[64][40];
    __shared__ __align__(16) unsigned short Bsh[64][40];
    const int tid  = threadIdx.x;
    const int lane = tid & 63;
    const int w    = tid >> 6;
    const int wm   = w & 1, wn = w >> 1;
    const int row0 = blockIdx.x * 64;
    const int col0 = blockIdx.y * 64;
    const int srow = tid >> 2;
    const int sseg = (tid & 3) * 8;
    const int lrow = lane & 15;
    const int lk   = (lane >> 4) * 8;

    f32x4 acc[2][2] = {};

    for (int k0 = 0; k0 < 1024; k0 += 32) {
        __syncthreads();
        *(uint4*)&Ash[srow][sseg] = *(const uint4*)&A[(size_t)(row0 + srow) * 1024 + k0 + sseg];
        *(uint4*)&Bsh[srow][sseg] = *(const uint4*)&W[(size_t)(col0 + srow) * 1024 + k0 + sseg];
        __syncthreads();
        bf16x8 af[2], bfrag[2];
        af[0]    = *(const bf16x8*)&Ash[wm * 32 + lrow     ][lk];
        af[1]    = *(const bf16x8*)&Ash[wm * 32 + 16 + lrow][lk];
        bfrag[0] = *(const bf16x8*)&Bsh[wn * 32 + lrow     ][lk];
        bfrag[1] = *(const bf16x8*)&Bsh[wn * 32 + 16 + lrow][lk];
        #pragma unroll
        for (int i = 0; i < 2; i++)
            #pragma unroll
            for (int j = 0; j < 2; j++)
                acc[i][j] = __builtin_amdgcn_mfma_f32_16x16x32_bf16(af[i], bfrag[j], acc[i][j], 0, 0, 0);
    }

    #pragma unroll
    for (int i = 0; i < 2; i++) {
        int r = row0 + wm * 32 + i * 16 + (lane >> 4) * 4;
        #pragma unroll
        for (int j = 0; j < 2; j++) {
            int cc = col0 + wn * 32 + j * 16 + (lane & 15);
            float bsum = bih[cc] + bhh[cc];
            #pragma unroll
            for (int rr = 0; rr < 4; rr++)
                C[(size_t)(r + rr) * 4096 + cc] = f2bf(acc[i][j][rr] + bsum);
        }
    }
}

// Persistent recurrence for one layer: PLAIN launch, 64 blocks x 256 thr.
// Co-residency by capacity: 64 blocks on 256 CUs can never wait on each other.
// Inter-block h exchange via RELAXED agent-scope atomics (coherent at L3 -> no
// fences, no L2 wb/inv). Barrier: every wave drains stores (vmcnt(0)), block
// syncs, tid0 does one relaxed fetch_add and spins on the monotone counter.
// Block owns m in [m0,m0+16); wave w owns 16 gate-cols vc=w*16+n over full K,
// weights in wreg[32] (128 VGPR/lane target). LDS footprint = 76288 B (R2-proven).
__global__ __launch_bounds__(256, 1) void lstm_layer(
    const unsigned short* __restrict__ Whh,    // 4096 x 1024 bf16 (this layer)
    const unsigned short* __restrict__ xproj,  // (B,T,4M) bf16, bias folded
    unsigned short* __restrict__ h0buf,        // 32x1024 bf16 parity-0 (h_init)
    unsigned short* __restrict__ h1buf,        // 32x1024 bf16 parity-1
    const float* __restrict__ c0,              // 32x1024 f32 initial c
    float* __restrict__ hF, float* __restrict__ cF,   // final states -> d_out
    unsigned short* __restrict__ seq_bf,       // (B,T,M) bf16 or null
    float* __restrict__ seq_f32,               // (B,T,M) f32 or null
    unsigned int* bar, unsigned int bar_base)
{
    __shared__ __align__(16) unsigned short hsh[32][1032];  // 66048 B
    __shared__ __align__(16) float gsh[4][32][20];          // 10240 B

    const int tid  = threadIdx.x;
    const int lane = tid & 63;
    const int w    = tid >> 6;
    const int m0   = blockIdx.x * 16;
    const int n    = lane & 15;
    const int lk   = (lane >> 4) * 8;

    // wave w owns cols vc = w*16 + n; vc = 4*mi + g
    const int vc = w * 16 + n;
    const size_t jrow = (size_t)((vc & 3) * 1024 + m0 + (vc >> 2));

    // weights resident in VGPRs (full K for our column)
    bf16x8 wreg[32];
    #pragma unroll
    for (int kc = 0; kc < 32; kc++)
        wreg[kc] = *(const bf16x8*)&Whh[jrow * 1024 + kc * 32 + lk];

    // epilogue ownership: thread -> (batch eb, adjacent m-pair em,em+1)
    const int eb = lane >> 1;                  // 0..31
    const int q  = lane & 1;                   // m-pair slot within wave
    const int em = m0 + 4 * w + 2 * q;         // even
    float2 creg = *(const float2*)&c0[eb * 1024 + em];
    float2 hlast = {0.f, 0.f};

    #pragma unroll 1
    for (int t = 0; t < 256; t++) {
        unsigned short* hin  = (t & 1) ? h1buf : h0buf;
        unsigned short* hout = (t & 1) ? h0buf : h1buf;

        // xproj prefetch (independent of h; hides HBM latency behind staging)
        const size_t xb = ((size_t)eb * 256 + t) * 4096 + em;
        unsigned xu0 = *(const unsigned*)&xproj[xb];
        unsigned xu1 = *(const unsigned*)&xproj[xb + 1024];
        unsigned xu2 = *(const unsigned*)&xproj[xb + 2048];
        unsigned xu3 = *(const unsigned*)&xproj[xb + 3072];

        // stage h 32x1024 bf16: 32 coalesced 8B agent-scope atomic loads/thread
        #pragma unroll
        for (int s = 0; s < 32; s++) {
            unsigned long long v = __hip_atomic_load(
                (unsigned long long*)hin + s * 256 + tid,
                __ATOMIC_RELAXED, __HIP_MEMORY_SCOPE_AGENT);
            *(unsigned long long*)&hsh[s][tid * 4] = v;
        }
        __syncthreads();

        // gates GEMM: full K, 4 independent MFMA chains (K-parity x batch-half)
        f32x4 ae0 = {}, ae1 = {}, ao0 = {}, ao1 = {};
        #pragma unroll
        for (int kc = 0; kc < 32; kc += 2) {
            bf16x8 a00 = *(const bf16x8*)&hsh[n     ][kc * 32 + lk];
            bf16x8 a01 = *(const bf16x8*)&hsh[16 + n][kc * 32 + lk];
            ae0 = __builtin_amdgcn_mfma_f32_16x16x32_bf16(a00, wreg[kc], ae0, 0, 0, 0);
            ae1 = __builtin_amdgcn_mfma_f32_16x16x32_bf16(a01, wreg[kc], ae1, 0, 0, 0);
            bf16x8 a10 = *(const bf16x8*)&hsh[n     ][(kc + 1) * 32 + lk];
            bf16x8 a11 = *(const bf16x8*)&hsh[16 + n][(kc + 1) * 32 + lk];
            ao0 = __builtin_amdgcn_mfma_f32_16x16x32_bf16(a10, wreg[kc + 1], ao0, 0, 0, 0);
            ao1 = __builtin_amdgcn_mfma_f32_16x16x32_bf16(a11, wreg[kc + 1], ao1, 0, 0, 0);
        }
        f32x4 acc0 = ae0 + ao0;
        f32x4 acc1 = ae1 + ao1;

        // wave-LOCAL gate exchange (only wave w reads gsh[w]) -> no barrier
        {
            int br = (lane >> 4) * 4;
            #pragma unroll
            for (int r = 0; r < 4; r++) {
                gsh[w][br + r][n]      = acc0[r];   // C/D: col=n, row=batch
                gsh[w][16 + br + r][n] = acc1[r];
            }
        }

        // epilogue: thread (eb, q) -> gates at local cols [8q, 8q+8)
        f32x4 ga = *(const f32x4*)&gsh[w][eb][8 * q];       // i,f,g,o for em
        f32x4 gb = *(const f32x4*)&gsh[w][eb][8 * q + 4];   // i,f,g,o for em+1

        float gi0 = ga[0] + bf2f((unsigned short)(xu0 & 0xffff));
        float gf0 = ga[1] + bf2f((unsigned short)(xu1 & 0xffff));
        float gg0 = ga[2] + bf2f((unsigned short)(xu2 & 0xffff));
        float go0 = ga[3] + bf2f((unsigned short)(xu3 & 0xffff));
        float gi1 = gb[0] + bf2f((unsigned short)(xu0 >> 16));
        float gf1 = gb[1] + bf2f((unsigned short)(xu1 >> 16));
        float gg1 = gb[2] + bf2f((unsigned short)(xu2 >> 16));
        float go1 = gb[3] + bf2f((unsigned short)(xu3 >> 16));

        float c0n = sigmoidf_fast(gf0) * creg.x + sigmoidf_fast(gi0) * tanhf_fast(gg0);
        float c1n = sigmoidf_fast(gf1) * creg.y + sigmoidf_fast(gi1) * tanhf_fast(gg1);
        float h0v = sigmoidf_fast(go0) * tanhf_fast(c0n);
        float h1v = sigmoidf_fast(go1) * tanhf_fast(c1n);
        creg.x = c0n; creg.y = c1n;
        hlast.x = h0v; hlast.y = h1v;

        unsigned hp = (unsigned)f2bf(h0v) | ((unsigned)f2bf(h1v) << 16);
        __hip_atomic_store((unsigned*)&hout[eb * 1024 + em], hp,
                           __ATOMIC_RELAXED, __HIP_MEMORY_SCOPE_AGENT);
        if (seq_bf)  *(unsigned*)&seq_bf[((size_t)eb * 256 + t) * 1024 + em] = hp;
        if (seq_f32) {
            float2 hv2 = {h0v, h1v};
            *(float2*)&seq_f32[((size_t)eb * 256 + t) * 1024 + em] = hv2;
        }

        // barrier: drain this wave's stores to coherence point, block-sync
        // (all waves drained), one arrive+spin per block, release via sync.
        asm volatile("s_waitcnt vmcnt(0)" ::: "memory");
        __syncthreads();
        if (tid == 0) {
            __hip_atomic_fetch_add(bar, 1u, __ATOMIC_RELAXED, __HIP_MEMORY_SCOPE_AGENT);
            unsigned tgt = bar_base + 64u * (unsigned)(t + 1);
            while (__hip_atomic_load(bar, __ATOMIC_RELAXED, __HIP_MEMORY_SCOPE_AGENT) < tgt)
                __builtin_amdgcn_s_sleep(1);
        }
        __syncthreads();
    }

    float2 hf2 = {hlast.x, hlast.y};
    *(float2*)&hF[eb * 1024 + em] = hf2;
    float2 cf2 = {creg.x, creg.y};
    *(float2*)&cF[eb * 1024 + em] = cf2;
}

extern "C" void kernel_launch(void* const* d_in, const int* in_sizes, int n_in,
                              void* d_out, int out_size, void* d_ws, size_t ws_size,
                              hipStream_t stream)
{
    const float* x   = (const float*)d_in[0];
    const float* h0  = (const float*)d_in[1];
    const float* c0  = (const float*)d_in[2];
    const float* Wih = (const float*)d_in[3];
    const float* Whh = (const float*)d_in[4];
    const float* bih = (const float*)d_in[5];
    const float* bhh = (const float*)d_in[6];
    float* out = (float*)d_out;

    char* p = (char*)d_ws;
    unsigned short* Xproj = (unsigned short*)p; p += (size_t)8192 * 4096 * 2;
    unsigned short* xbf   = (unsigned short*)p; p += (size_t)8192 * 1024 * 2;
    unsigned short* seqbf = (unsigned short*)p; p += (size_t)8192 * 1024 * 2;
    unsigned short* Wihbf = (unsigned short*)p; p += (size_t)2 * 4096 * 1024 * 2;
    unsigned short* Whhbf = (unsigned short*)p; p += (size_t)2 * 4096 * 1024 * 2;
    unsigned short* hbfA  = (unsigned short*)p; p += (size_t)2 * 32 * 1024 * 2;
    unsigned short* hbfB  = (unsigned short*)p; p += (size_t)32 * 1024 * 2;
    unsigned int*   bar   = (unsigned int*)p;   p += 128;

    hipMemsetAsync(bar, 0, 128, stream);
    cvt_f32_to_bf16<<<1024, 256, 0, stream>>>(x,   xbf,   8192 * 1024 / 4);
    cvt_f32_to_bf16<<<1024, 256, 0, stream>>>(Wih, Wihbf, 2 * 4096 * 1024 / 4);
    cvt_f32_to_bf16<<<1024, 256, 0, stream>>>(Whh, Whhbf, 2 * 4096 * 1024 / 4);
    cvt_f32_to_bf16<<<64,   256, 0, stream>>>(h0,  hbfA,  2 * 32 * 1024 / 4);

    for (int l = 0; l < 2; l++) {
        const unsigned short* Ain = (l == 0) ? xbf : seqbf;
        gemm_proj<<<dim3(128, 64), 256, 0, stream>>>(
            Ain, Wihbf + (size_t)l * 4096 * 1024, bih + l * 4096, bhh + l * 4096, Xproj);

        const unsigned short* Whl = Whhbf + (size_t)l * 4096 * 1024;
        unsigned short* h0l = hbfA + l * 32 * 1024;
        unsigned short* h1l = hbfB;
        const float*    c0l = c0  + l * 32 * 1024;
        float* hFl = out + (size_t)8192 * 1024 + l * 32 * 1024;
        float* cFl = out + (size_t)8192 * 1024 + 65536 + l * 32 * 1024;
        unsigned short* sb = (l == 0) ? seqbf : nullptr;
        float* sf          = (l == 1) ? out   : nullptr;
        unsigned int base  = (unsigned)(l * 256 * 64);

        lstm_layer<<<64, 256, 0, stream>>>(Whl, Xproj, h0l, h1l, c0l,
                                           hFl, cFl, sb, sf, bar, base);
    }
}

// Round 5
// 6199.450 us; speedup vs baseline: 1.2918x; 1.0429x over previous
//
#include <hip/hip_runtime.h>

// LSTM: L=2 layers, B=32, T=256, N=M=1024, gates 4M=4096
// d_in: x(B,T,N) h(L,B,M) c(L,B,M) Wih(L,4M,N) Whh(L,4M,M) bih(L,4M) bhh(L,4M), all fp32
// d_out: outs(B,T,M) ++ h_final(L,B,M) ++ c_final(L,B,M), fp32

typedef __bf16 bf16x8 __attribute__((ext_vector_type(8)));
typedef float  f32x4  __attribute__((ext_vector_type(4)));

__device__ __forceinline__ unsigned short f2bf(float f) {
    union { float f; unsigned u; } v; v.f = f;
    unsigned u = v.u;
    unsigned r = u + 0x7fffu + ((u >> 16) & 1u);   // RNE
    return (unsigned short)(r >> 16);
}
__device__ __forceinline__ float bf2f(unsigned short b) {
    union { unsigned u; float f; } v; v.u = ((unsigned)b) << 16;
    return v.f;
}
__device__ __forceinline__ float sigmoidf_fast(float x) {
    return 1.0f / (1.0f + __expf(-x));
}
__device__ __forceinline__ float tanhf_fast(float x) {
    return 1.0f - 2.0f / (__expf(2.0f * x) + 1.0f);
}

__global__ void cvt_f32_to_bf16(const float* __restrict__ src,
                                unsigned short* __restrict__ dst, int n4) {
    int i = blockIdx.x * blockDim.x + threadIdx.x;
    int stride = gridDim.x * blockDim.x;
    for (; i < n4; i += stride) {
        float4 v = ((const float4*)src)[i];
        ushort4 o;
        o.x = f2bf(v.x); o.y = f2bf(v.y); o.z = f2bf(v.z); o.w = f2bf(v.w);
        ((ushort4*)dst)[i] = o;
    }
}

// C[r][j] = sum_k A[r][k]*W[j][k] + bih[j] + bhh[j]   (NT GEMM)
__global__ __launch_bounds__(256) void gemm_proj(
    const unsigned short* __restrict__ A, const unsigned short* __restrict__ W,
    const float* __restrict__ bih, const float* __restrict__ bhh,
    unsigned short* __restrict__ C)
{
    __shared__ __align__(16) unsigned short Ash[64][40];
    __shared__ __align__(16) unsigned short Bsh[64][40];
    const int tid  = threadIdx.x;
    const int lane = tid & 63;
    const int w    = tid >> 6;
    const int wm   = w & 1, wn = w >> 1;
    const int row0 = blockIdx.x * 64;
    const int col0 = blockIdx.y * 64;
    const int srow = tid >> 2;
    const int sseg = (tid & 3) * 8;
    const int lrow = lane & 15;
    const int lk   = (lane >> 4) * 8;

    f32x4 acc[2][2] = {};

    for (int k0 = 0; k0 < 1024; k0 += 32) {
        __syncthreads();
        *(uint4*)&Ash[srow][sseg] = *(const uint4*)&A[(size_t)(row0 + srow) * 1024 + k0 + sseg];
        *(uint4*)&Bsh[srow][sseg] = *(const uint4*)&W[(size_t)(col0 + srow) * 1024 + k0 + sseg];
        __syncthreads();
        bf16x8 af[2], bfrag[2];
        af[0]    = *(const bf16x8*)&Ash[wm * 32 + lrow     ][lk];
        af[1]    = *(const bf16x8*)&Ash[wm * 32 + 16 + lrow][lk];
        bfrag[0] = *(const bf16x8*)&Bsh[wn * 32 + lrow     ][lk];
        bfrag[1] = *(const bf16x8*)&Bsh[wn * 32 + 16 + lrow][lk];
        #pragma unroll
        for (int i = 0; i < 2; i++)
            #pragma unroll
            for (int j = 0; j < 2; j++)
                acc[i][j] = __builtin_amdgcn_mfma_f32_16x16x32_bf16(af[i], bfrag[j], acc[i][j], 0, 0, 0);
    }

    #pragma unroll
    for (int i = 0; i < 2; i++) {
        int r = row0 + wm * 32 + i * 16 + (lane >> 4) * 4;
        #pragma unroll
        for (int j = 0; j < 2; j++) {
            int cc = col0 + wn * 32 + j * 16 + (lane & 15);
            float bsum = bih[cc] + bhh[cc];
            #pragma unroll
            for (int rr = 0; rr < 4; rr++)
                C[(size_t)(r + rr) * 4096 + cc] = f2bf(acc[i][j][rr] + bsum);
        }
    }
}

// Persistent recurrence, plain launch, 64 blocks x 256 thr (co-resident by
// capacity: 64 << 256 CUs). h exchange via relaxed agent-scope atomics
// (L3-coherent, fence-free). Barrier: DISTRIBUTED flags — block b stores
// flags[b*32]=t+1 (own cache line, parallel, no RMW), wave 0 polls all 64
// flags with ONE 64-lane gather + __all(). Central-counter RMW serialization
// (~10 us/step in R2/R4) is eliminated.
__global__ __launch_bounds__(256, 1) void lstm_layer(
    const unsigned short* __restrict__ Whh,    // 4096 x 1024 bf16 (this layer)
    const unsigned short* __restrict__ xproj,  // (B,T,4M) bf16, bias folded
    unsigned short* __restrict__ h0buf,        // 32x1024 bf16 parity-0 (h_init)
    unsigned short* __restrict__ h1buf,        // 32x1024 bf16 parity-1
    const float* __restrict__ c0,              // 32x1024 f32 initial c
    float* __restrict__ hF, float* __restrict__ cF,   // final states -> d_out
    unsigned short* __restrict__ seq_bf,       // (B,T,M) bf16 or null
    float* __restrict__ seq_f32,               // (B,T,M) f32 or null
    unsigned int* flags, unsigned int bar_base)
{
    __shared__ __align__(16) unsigned short hsh[32][1032];  // 66048 B
    __shared__ __align__(16) float gsh[4][32][20];          // 10240 B

    const int tid  = threadIdx.x;
    const int lane = tid & 63;
    const int w    = tid >> 6;
    const int m0   = blockIdx.x * 16;
    const int n    = lane & 15;
    const int lk   = (lane >> 4) * 8;

    // wave w owns cols vc = w*16 + n; vc = 4*mi + g
    const int vc = w * 16 + n;
    const size_t jrow = (size_t)((vc & 3) * 1024 + m0 + (vc >> 2));

    // weights (compiler may keep in VGPRs or reload from L2; own slice stays hot)
    bf16x8 wreg[32];
    #pragma unroll
    for (int kc = 0; kc < 32; kc++)
        wreg[kc] = *(const bf16x8*)&Whh[jrow * 1024 + kc * 32 + lk];

    // epilogue ownership: thread -> (batch eb, adjacent m-pair em,em+1)
    const int eb = lane >> 1;                  // 0..31
    const int q  = lane & 1;                   // m-pair slot within wave
    const int em = m0 + 4 * w + 2 * q;         // even
    float2 creg = *(const float2*)&c0[eb * 1024 + em];
    float2 hlast = {0.f, 0.f};

    #pragma unroll 1
    for (int t = 0; t < 256; t++) {
        unsigned short* hin  = (t & 1) ? h1buf : h0buf;
        unsigned short* hout = (t & 1) ? h0buf : h1buf;

        // xproj prefetch (independent of h; hides HBM latency behind staging)
        const size_t xb = ((size_t)eb * 256 + t) * 4096 + em;
        unsigned xu0 = *(const unsigned*)&xproj[xb];
        unsigned xu1 = *(const unsigned*)&xproj[xb + 1024];
        unsigned xu2 = *(const unsigned*)&xproj[xb + 2048];
        unsigned xu3 = *(const unsigned*)&xproj[xb + 3072];

        // stage h 32x1024 bf16: 32 coalesced 8B agent-scope atomic loads/thread
        #pragma unroll
        for (int s = 0; s < 32; s++) {
            unsigned long long v = __hip_atomic_load(
                (unsigned long long*)hin + s * 256 + tid,
                __ATOMIC_RELAXED, __HIP_MEMORY_SCOPE_AGENT);
            *(unsigned long long*)&hsh[s][tid * 4] = v;
        }
        __syncthreads();

        // gates GEMM: full K, 4 independent MFMA chains (K-parity x batch-half)
        f32x4 ae0 = {}, ae1 = {}, ao0 = {}, ao1 = {};
        #pragma unroll
        for (int kc = 0; kc < 32; kc += 2) {
            bf16x8 a00 = *(const bf16x8*)&hsh[n     ][kc * 32 + lk];
            bf16x8 a01 = *(const bf16x8*)&hsh[16 + n][kc * 32 + lk];
            ae0 = __builtin_amdgcn_mfma_f32_16x16x32_bf16(a00, wreg[kc], ae0, 0, 0, 0);
            ae1 = __builtin_amdgcn_mfma_f32_16x16x32_bf16(a01, wreg[kc], ae1, 0, 0, 0);
            bf16x8 a10 = *(const bf16x8*)&hsh[n     ][(kc + 1) * 32 + lk];
            bf16x8 a11 = *(const bf16x8*)&hsh[16 + n][(kc + 1) * 32 + lk];
            ao0 = __builtin_amdgcn_mfma_f32_16x16x32_bf16(a10, wreg[kc + 1], ao0, 0, 0, 0);
            ao1 = __builtin_amdgcn_mfma_f32_16x16x32_bf16(a11, wreg[kc + 1], ao1, 0, 0, 0);
        }
        f32x4 acc0 = ae0 + ao0;
        f32x4 acc1 = ae1 + ao1;

        // wave-LOCAL gate exchange (only wave w reads gsh[w]) -> no barrier
        {
            int br = (lane >> 4) * 4;
            #pragma unroll
            for (int r = 0; r < 4; r++) {
                gsh[w][br + r][n]      = acc0[r];   // C/D: col=n, row=batch
                gsh[w][16 + br + r][n] = acc1[r];
            }
        }

        // epilogue: thread (eb, q) -> gates at local cols [8q, 8q+8)
        f32x4 ga = *(const f32x4*)&gsh[w][eb][8 * q];       // i,f,g,o for em
        f32x4 gb = *(const f32x4*)&gsh[w][eb][8 * q + 4];   // i,f,g,o for em+1

        float gi0 = ga[0] + bf2f((unsigned short)(xu0 & 0xffff));
        float gf0 = ga[1] + bf2f((unsigned short)(xu1 & 0xffff));
        float gg0 = ga[2] + bf2f((unsigned short)(xu2 & 0xffff));
        float go0 = ga[3] + bf2f((unsigned short)(xu3 & 0xffff));
        float gi1 = gb[0] + bf2f((unsigned short)(xu0 >> 16));
        float gf1 = gb[1] + bf2f((unsigned short)(xu1 >> 16));
        float gg1 = gb[2] + bf2f((unsigned short)(xu2 >> 16));
        float go1 = gb[3] + bf2f((unsigned short)(xu3 >> 16));

        float c0n = sigmoidf_fast(gf0) * creg.x + sigmoidf_fast(gi0) * tanhf_fast(gg0);
        float c1n = sigmoidf_fast(gf1) * creg.y + sigmoidf_fast(gi1) * tanhf_fast(gg1);
        float h0v = sigmoidf_fast(go0) * tanhf_fast(c0n);
        float h1v = sigmoidf_fast(go1) * tanhf_fast(c1n);
        creg.x = c0n; creg.y = c1n;
        hlast.x = h0v; hlast.y = h1v;

        unsigned hp = (unsigned)f2bf(h0v) | ((unsigned)f2bf(h1v) << 16);
        __hip_atomic_store((unsigned*)&hout[eb * 1024 + em], hp,
                           __ATOMIC_RELAXED, __HIP_MEMORY_SCOPE_AGENT);
        if (seq_bf)  *(unsigned*)&seq_bf[((size_t)eb * 256 + t) * 1024 + em] = hp;
        if (seq_f32) {
            float2 hv2 = {h0v, h1v};
            *(float2*)&seq_f32[((size_t)eb * 256 + t) * 1024 + em] = hv2;
        }

        // ---- distributed barrier ----
        // each wave drains its h-stores to the coherence point, block-sync,
        // block arrives on its OWN flag line (no RMW), wave 0 polls all 64
        // flags with one 64-lane gather.
        asm volatile("s_waitcnt vmcnt(0)" ::: "memory");
        __syncthreads();
        if (tid < 64) {
            const unsigned tgt = bar_base + (unsigned)(t + 1);
            if (tid == 0)
                __hip_atomic_store(flags + (size_t)blockIdx.x * 32, tgt,
                                   __ATOMIC_RELAXED, __HIP_MEMORY_SCOPE_AGENT);
            const unsigned* fp = flags + (size_t)tid * 32;
            while (true) {
                unsigned v = __hip_atomic_load(fp, __ATOMIC_RELAXED,
                                               __HIP_MEMORY_SCOPE_AGENT);
                if (__all((int)(v >= tgt))) break;
                __builtin_amdgcn_s_sleep(1);
            }
        }
        __syncthreads();
    }

    float2 hf2 = {hlast.x, hlast.y};
    *(float2*)&hF[eb * 1024 + em] = hf2;
    float2 cf2 = {creg.x, creg.y};
    *(float2*)&cF[eb * 1024 + em] = cf2;
}

extern "C" void kernel_launch(void* const* d_in, const int* in_sizes, int n_in,
                              void* d_out, int out_size, void* d_ws, size_t ws_size,
                              hipStream_t stream)
{
    const float* x   = (const float*)d_in[0];
    const float* h0  = (const float*)d_in[1];
    const float* c0  = (const float*)d_in[2];
    const float* Wih = (const float*)d_in[3];
    const float* Whh = (const float*)d_in[4];
    const float* bih = (const float*)d_in[5];
    const float* bhh = (const float*)d_in[6];
    float* out = (float*)d_out;

    char* p = (char*)d_ws;
    unsigned short* Xproj = (unsigned short*)p; p += (size_t)8192 * 4096 * 2;
    unsigned short* xbf   = (unsigned short*)p; p += (size_t)8192 * 1024 * 2;
    unsigned short* seqbf = (unsigned short*)p; p += (size_t)8192 * 1024 * 2;
    unsigned short* Wihbf = (unsigned short*)p; p += (size_t)2 * 4096 * 1024 * 2;
    unsigned short* Whhbf = (unsigned short*)p; p += (size_t)2 * 4096 * 1024 * 2;
    unsigned short* hbfA  = (unsigned short*)p; p += (size_t)2 * 32 * 1024 * 2;
    unsigned short* hbfB  = (unsigned short*)p; p += (size_t)32 * 1024 * 2;
    unsigned int*   flags = (unsigned int*)p;   p += 64 * 128;   // 64 flag lines

    hipMemsetAsync(flags, 0, 64 * 128, stream);
    cvt_f32_to_bf16<<<1024, 256, 0, stream>>>(x,   xbf,   8192 * 1024 / 4);
    cvt_f32_to_bf16<<<1024, 256, 0, stream>>>(Wih, Wihbf, 2 * 4096 * 1024 / 4);
    cvt_f32_to_bf16<<<1024, 256, 0, stream>>>(Whh, Whhbf, 2 * 4096 * 1024 / 4);
    cvt_f32_to_bf16<<<64,   256, 0, stream>>>(h0,  hbfA,  2 * 32 * 1024 / 4);

    for (int l = 0; l < 2; l++) {
        const unsigned short* Ain = (l == 0) ? xbf : seqbf;
        gemm_proj<<<dim3(128, 64), 256, 0, stream>>>(
            Ain, Wihbf + (size_t)l * 4096 * 1024, bih + l * 4096, bhh + l * 4096, Xproj);

        const unsigned short* Whl = Whhbf + (size_t)l * 4096 * 1024;
        unsigned short* h0l = hbfA + l * 32 * 1024;
        unsigned short* h1l = hbfB;
        const float*    c0l = c0  + l * 32 * 1024;
        float* hFl = out + (size_t)8192 * 1024 + l * 32 * 1024;
        float* cFl = out + (size_t)8192 * 1024 + 65536 + l * 32 * 1024;
        unsigned short* sb = (l == 0) ? seqbf : nullptr;
        float* sf          = (l == 1) ? out   : nullptr;
        unsigned int base  = (unsigned)(l * 256);

        lstm_layer<<<64, 256, 0, stream>>>(Whl, Xproj, h0l, h1l, c0l,
                                           hFl, cFl, sb, sf, flags, base);
    }
}

// Round 6
// 2911.894 us; speedup vs baseline: 2.7503x; 2.1290x over previous
//
#include <hip/hip_runtime.h>

// LSTM: L=2 layers, B=32, T=256, N=M=1024, gates 4M=4096
// d_in: x(B,T,N) h(L,B,M) c(L,B,M) Wih(L,4M,N) Whh(L,4M,M) bih(L,4M) bhh(L,4M), all fp32
// d_out: outs(B,T,M) ++ h_final(L,B,M) ++ c_final(L,B,M), fp32

typedef __bf16 bf16x8 __attribute__((ext_vector_type(8)));
typedef float  f32x4  __attribute__((ext_vector_type(4)));
typedef unsigned u32x4 __attribute__((ext_vector_type(4)));

__device__ __forceinline__ unsigned short f2bf(float f) {
    union { float f; unsigned u; } v; v.f = f;
    unsigned u = v.u;
    unsigned r = u + 0x7fffu + ((u >> 16) & 1u);   // RNE
    return (unsigned short)(r >> 16);
}
__device__ __forceinline__ float bf2f(unsigned short b) {
    union { unsigned u; float f; } v; v.u = ((unsigned)b) << 16;
    return v.f;
}
__device__ __forceinline__ float sigmoidf_fast(float x) {
    return 1.0f / (1.0f + __expf(-x));
}
__device__ __forceinline__ float tanhf_fast(float x) {
    return 1.0f - 2.0f / (__expf(2.0f * x) + 1.0f);
}

__global__ void cvt_f32_to_bf16(const float* __restrict__ src,
                                unsigned short* __restrict__ dst, int n4) {
    int i = blockIdx.x * blockDim.x + threadIdx.x;
    int stride = gridDim.x * blockDim.x;
    for (; i < n4; i += stride) {
        float4 v = ((const float4*)src)[i];
        ushort4 o;
        o.x = f2bf(v.x); o.y = f2bf(v.y); o.z = f2bf(v.z); o.w = f2bf(v.w);
        ((ushort4*)dst)[i] = o;
    }
}

// C[r][j] = sum_k A[r][k]*W[j][k] + bih[j] + bhh[j]   (NT GEMM)
__global__ __launch_bounds__(256) void gemm_proj(
    const unsigned short* __restrict__ A, const unsigned short* __restrict__ W,
    const float* __restrict__ bih, const float* __restrict__ bhh,
    unsigned short* __restrict__ C)
{
    __shared__ __align__(16) unsigned short Ash[64][40];
    __shared__ __align__(16) unsigned short Bsh[64][40];
    const int tid  = threadIdx.x;
    const int lane = tid & 63;
    const int w    = tid >> 6;
    const int wm   = w & 1, wn = w >> 1;
    const int row0 = blockIdx.x * 64;
    const int col0 = blockIdx.y * 64;
    const int srow = tid >> 2;
    const int sseg = (tid & 3) * 8;
    const int lrow = lane & 15;
    const int lk   = (lane >> 4) * 8;

    f32x4 acc[2][2] = {};

    for (int k0 = 0; k0 < 1024; k0 += 32) {
        __syncthreads();
        *(uint4*)&Ash[srow][sseg] = *(const uint4*)&A[(size_t)(row0 + srow) * 1024 + k0 + sseg];
        *(uint4*)&Bsh[srow][sseg] = *(const uint4*)&W[(size_t)(col0 + srow) * 1024 + k0 + sseg];
        __syncthreads();
        bf16x8 af[2], bfrag[2];
        af[0]    = *(const bf16x8*)&Ash[wm * 32 + lrow     ][lk];
        af[1]    = *(const bf16x8*)&Ash[wm * 32 + 16 + lrow][lk];
        bfrag[0] = *(const bf16x8*)&Bsh[wn * 32 + lrow     ][lk];
        bfrag[1] = *(const bf16x8*)&Bsh[wn * 32 + 16 + lrow][lk];
        #pragma unroll
        for (int i = 0; i < 2; i++)
            #pragma unroll
            for (int j = 0; j < 2; j++)
                acc[i][j] = __builtin_amdgcn_mfma_f32_16x16x32_bf16(af[i], bfrag[j], acc[i][j], 0, 0, 0);
    }

    #pragma unroll
    for (int i = 0; i < 2; i++) {
        int r = row0 + wm * 32 + i * 16 + (lane >> 4) * 4;
        #pragma unroll
        for (int j = 0; j < 2; j++) {
            int cc = col0 + wn * 32 + j * 16 + (lane & 15);
            float bsum = bih[cc] + bhh[cc];
            #pragma unroll
            for (int rr = 0; rr < 4; rr++)
                C[(size_t)(r + rr) * 4096 + cc] = f2bf(acc[i][j][rr] + bsum);
        }
    }
}

// Persistent recurrence, plain launch, 64 blocks x 256 thr (co-resident by
// capacity). h exchange: producer stores via agent-scope atomics (write-through
// to L3); consumer stages via BATCHED inline-asm global_load_dwordx4 sc0 sc1
// (cache-bypass, 16 back-to-back loads -> ONE L3 latency, not 32 serialized
// round-trips, which was the ~10us/step cost in R4/R5). No data race: the
// distributed flag barrier orders producer/consumer; bypass flags only defeat
// stale L1/L2. Barrier: per-block flag line + one 64-lane gather poll.
__global__ __launch_bounds__(256, 1) void lstm_layer(
    const unsigned short* __restrict__ Whh,    // 4096 x 1024 bf16 (this layer)
    const unsigned short* __restrict__ xproj,  // (B,T,4M) bf16, bias folded
    unsigned short* __restrict__ h0buf,        // 32x1024 bf16 parity-0 (h_init)
    unsigned short* __restrict__ h1buf,        // 32x1024 bf16 parity-1
    const float* __restrict__ c0,              // 32x1024 f32 initial c
    float* __restrict__ hF, float* __restrict__ cF,   // final states -> d_out
    unsigned short* __restrict__ seq_bf,       // (B,T,M) bf16 or null
    float* __restrict__ seq_f32,               // (B,T,M) f32 or null
    unsigned int* flags, unsigned int bar_base)
{
    __shared__ __align__(16) unsigned short hsh[32][1032];  // 66048 B
    __shared__ __align__(16) float gsh[4][32][20];          // 10240 B

    const int tid  = threadIdx.x;
    const int lane = tid & 63;
    const int w    = tid >> 6;
    const int m0   = blockIdx.x * 16;
    const int n    = lane & 15;
    const int lk   = (lane >> 4) * 8;

    // wave w owns cols vc = w*16 + n; vc = 4*mi + g
    const int vc = w * 16 + n;
    const size_t jrow = (size_t)((vc & 3) * 1024 + m0 + (vc >> 2));

    bf16x8 wreg[32];
    #pragma unroll
    for (int kc = 0; kc < 32; kc++)
        wreg[kc] = *(const bf16x8*)&Whh[jrow * 1024 + kc * 32 + lk];

    // epilogue ownership: thread -> (batch eb, adjacent m-pair em,em+1)
    const int eb = lane >> 1;                  // 0..31
    const int q  = lane & 1;
    const int em = m0 + 4 * w + 2 * q;
    float2 creg = *(const float2*)&c0[eb * 1024 + em];
    float2 hlast = {0.f, 0.f};

    // staging geometry: 16 rounds x 16B/thread; round s covers rows 2s,2s+1
    const int srow0 = tid >> 7;                // 0 or 1
    const int scol  = (tid & 127) * 8;         // elems

    #pragma unroll 1
    for (int t = 0; t < 256; t++) {
        unsigned short* hin  = (t & 1) ? h1buf : h0buf;
        unsigned short* hout = (t & 1) ? h0buf : h1buf;

        // xproj prefetch (independent of h)
        const size_t xb = ((size_t)eb * 256 + t) * 4096 + em;
        unsigned xu0 = *(const unsigned*)&xproj[xb];
        unsigned xu1 = *(const unsigned*)&xproj[xb + 1024];
        unsigned xu2 = *(const unsigned*)&xproj[xb + 2048];
        unsigned xu3 = *(const unsigned*)&xproj[xb + 3072];

        // ---- batched cache-bypass staging: 16 loads, ONE waitcnt, 16 LDS writes
        u32x4 hv[16];
        #pragma unroll
        for (int s = 0; s < 16; s++) {
            const void* ap = (const char*)hin + s * 4096 + tid * 16;
            asm volatile("global_load_dwordx4 %0, %1, off sc0 sc1"
                         : "=v"(hv[s]) : "v"(ap) : "memory");
        }
        asm volatile("s_waitcnt vmcnt(0)" ::: "memory");
        #pragma unroll
        for (int s = 0; s < 16; s++)
            *(u32x4*)&hsh[s * 2 + srow0][scol] = hv[s];
        __syncthreads();

        // gates GEMM: full K, 4 independent MFMA chains (K-parity x batch-half)
        f32x4 ae0 = {}, ae1 = {}, ao0 = {}, ao1 = {};
        #pragma unroll
        for (int kc = 0; kc < 32; kc += 2) {
            bf16x8 a00 = *(const bf16x8*)&hsh[n     ][kc * 32 + lk];
            bf16x8 a01 = *(const bf16x8*)&hsh[16 + n][kc * 32 + lk];
            ae0 = __builtin_amdgcn_mfma_f32_16x16x32_bf16(a00, wreg[kc], ae0, 0, 0, 0);
            ae1 = __builtin_amdgcn_mfma_f32_16x16x32_bf16(a01, wreg[kc], ae1, 0, 0, 0);
            bf16x8 a10 = *(const bf16x8*)&hsh[n     ][(kc + 1) * 32 + lk];
            bf16x8 a11 = *(const bf16x8*)&hsh[16 + n][(kc + 1) * 32 + lk];
            ao0 = __builtin_amdgcn_mfma_f32_16x16x32_bf16(a10, wreg[kc + 1], ao0, 0, 0, 0);
            ao1 = __builtin_amdgcn_mfma_f32_16x16x32_bf16(a11, wreg[kc + 1], ao1, 0, 0, 0);
        }
        f32x4 acc0 = ae0 + ao0;
        f32x4 acc1 = ae1 + ao1;

        // wave-LOCAL gate exchange (only wave w reads gsh[w])
        {
            int br = (lane >> 4) * 4;
            #pragma unroll
            for (int r = 0; r < 4; r++) {
                gsh[w][br + r][n]      = acc0[r];   // C/D: col=n, row=batch
                gsh[w][16 + br + r][n] = acc1[r];
            }
        }

        // epilogue: thread (eb, q) -> gates at local cols [8q, 8q+8)
        f32x4 ga = *(const f32x4*)&gsh[w][eb][8 * q];
        f32x4 gb = *(const f32x4*)&gsh[w][eb][8 * q + 4];

        float gi0 = ga[0] + bf2f((unsigned short)(xu0 & 0xffff));
        float gf0 = ga[1] + bf2f((unsigned short)(xu1 & 0xffff));
        float gg0 = ga[2] + bf2f((unsigned short)(xu2 & 0xffff));
        float go0 = ga[3] + bf2f((unsigned short)(xu3 & 0xffff));
        float gi1 = gb[0] + bf2f((unsigned short)(xu0 >> 16));
        float gf1 = gb[1] + bf2f((unsigned short)(xu1 >> 16));
        float gg1 = gb[2] + bf2f((unsigned short)(xu2 >> 16));
        float go1 = gb[3] + bf2f((unsigned short)(xu3 >> 16));

        float c0n = sigmoidf_fast(gf0) * creg.x + sigmoidf_fast(gi0) * tanhf_fast(gg0);
        float c1n = sigmoidf_fast(gf1) * creg.y + sigmoidf_fast(gi1) * tanhf_fast(gg1);
        float h0v = sigmoidf_fast(go0) * tanhf_fast(c0n);
        float h1v = sigmoidf_fast(go1) * tanhf_fast(c1n);
        creg.x = c0n; creg.y = c1n;
        hlast.x = h0v; hlast.y = h1v;

        unsigned hp = (unsigned)f2bf(h0v) | ((unsigned)f2bf(h1v) << 16);
        __hip_atomic_store((unsigned*)&hout[eb * 1024 + em], hp,
                           __ATOMIC_RELAXED, __HIP_MEMORY_SCOPE_AGENT);
        if (seq_bf)  *(unsigned*)&seq_bf[((size_t)eb * 256 + t) * 1024 + em] = hp;
        if (seq_f32) {
            float2 hv2 = {h0v, h1v};
            *(float2*)&seq_f32[((size_t)eb * 256 + t) * 1024 + em] = hv2;
        }

        // ---- distributed barrier: drain stores, arrive on own line, gather-poll
        asm volatile("s_waitcnt vmcnt(0)" ::: "memory");
        __syncthreads();
        if (tid < 64) {
            const unsigned tgt = bar_base + (unsigned)(t + 1);
            if (tid == 0)
                __hip_atomic_store(flags + (size_t)blockIdx.x * 32, tgt,
                                   __ATOMIC_RELAXED, __HIP_MEMORY_SCOPE_AGENT);
            const unsigned* fp = flags + (size_t)tid * 32;
            while (true) {
                unsigned v = __hip_atomic_load(fp, __ATOMIC_RELAXED,
                                               __HIP_MEMORY_SCOPE_AGENT);
                if (__all((int)(v >= tgt))) break;
                __builtin_amdgcn_s_sleep(1);
            }
        }
        __syncthreads();
    }

    float2 hf2 = {hlast.x, hlast.y};
    *(float2*)&hF[eb * 1024 + em] = hf2;
    float2 cf2 = {creg.x, creg.y};
    *(float2*)&cF[eb * 1024 + em] = cf2;
}

extern "C" void kernel_launch(void* const* d_in, const int* in_sizes, int n_in,
                              void* d_out, int out_size, void* d_ws, size_t ws_size,
                              hipStream_t stream)
{
    const float* x   = (const float*)d_in[0];
    const float* h0  = (const float*)d_in[1];
    const float* c0  = (const float*)d_in[2];
    const float* Wih = (const float*)d_in[3];
    const float* Whh = (const float*)d_in[4];
    const float* bih = (const float*)d_in[5];
    const float* bhh = (const float*)d_in[6];
    float* out = (float*)d_out;

    char* p = (char*)d_ws;
    unsigned short* Xproj = (unsigned short*)p; p += (size_t)8192 * 4096 * 2;
    unsigned short* xbf   = (unsigned short*)p; p += (size_t)8192 * 1024 * 2;
    unsigned short* seqbf = (unsigned short*)p; p += (size_t)8192 * 1024 * 2;
    unsigned short* Wihbf = (unsigned short*)p; p += (size_t)2 * 4096 * 1024 * 2;
    unsigned short* Whhbf = (unsigned short*)p; p += (size_t)2 * 4096 * 1024 * 2;
    unsigned short* hbfA  = (unsigned short*)p; p += (size_t)2 * 32 * 1024 * 2;
    unsigned short* hbfB  = (unsigned short*)p; p += (size_t)32 * 1024 * 2;
    unsigned int*   flags = (unsigned int*)p;   p += 64 * 128;   // 64 flag lines

    hipMemsetAsync(flags, 0, 64 * 128, stream);
    cvt_f32_to_bf16<<<1024, 256, 0, stream>>>(x,   xbf,   8192 * 1024 / 4);
    cvt_f32_to_bf16<<<1024, 256, 0, stream>>>(Wih, Wihbf, 2 * 4096 * 1024 / 4);
    cvt_f32_to_bf16<<<1024, 256, 0, stream>>>(Whh, Whhbf, 2 * 4096 * 1024 / 4);
    cvt_f32_to_bf16<<<64,   256, 0, stream>>>(h0,  hbfA,  2 * 32 * 1024 / 4);

    for (int l = 0; l < 2; l++) {
        const unsigned short* Ain = (l == 0) ? xbf : seqbf;
        gemm_proj<<<dim3(128, 64), 256, 0, stream>>>(
            Ain, Wihbf + (size_t)l * 4096 * 1024, bih + l * 4096, bhh + l * 4096, Xproj);

        const unsigned short* Whl = Whhbf + (size_t)l * 4096 * 1024;
        unsigned short* h0l = hbfA + l * 32 * 1024;
        unsigned short* h1l = hbfB;
        const float*    c0l = c0  + l * 32 * 1024;
        float* hFl = out + (size_t)8192 * 1024 + l * 32 * 1024;
        float* cFl = out + (size_t)8192 * 1024 + 65536 + l * 32 * 1024;
        unsigned short* sb = (l == 0) ? seqbf : nullptr;
        float* sf          = (l == 1) ? out   : nullptr;
        unsigned int base  = (unsigned)(l * 256);

        lstm_layer<<<64, 256, 0, stream>>>(Whl, Xproj, h0l, h1l, c0l,
                                           hFl, cFl, sb, sf, flags, base);
    }
}